// Round 2
// baseline (294.021 us; speedup 1.0000x reference)
//
#include <hip/hip_runtime.h>
#include <hip/hip_bf16.h>

#define MPTS  50000
#define NCH   128     // C
#define NH    32      // neighborhood
#define NK2   512     // H * CPG
#define NEG   0.1f
#define BN_EPS 1e-5f
#define K1_BLOCKS 1563        // ceil(50000/32); 1563*32 = 50016
#define TPAD_ROWS 50048

typedef __attribute__((ext_vector_type(8))) short        short8;   // 8 bf16 (4 VGPRs) - MFMA A/B frag
typedef __attribute__((ext_vector_type(4))) float        float4v;  // MFMA C/D frag
typedef __attribute__((ext_vector_type(2))) unsigned int uint2v;

__device__ __forceinline__ short f2b(float f) {
    __hip_bfloat16 h = __float2bfloat16(f);
    return *reinterpret_cast<short*>(&h);
}
__device__ __forceinline__ float b2f(short s) {
    unsigned int u = ((unsigned int)(unsigned short)s) << 16;
    return *reinterpret_cast<float*>(&u);
}

// ---------------------------------------------------------------------------
// k0: pre-pack weights into B-fragment-linear bf16 order:
//   wf[((nt*4 + ks)*64 + lane)*8 + i] = w[(ks*32 + (lane>>4)*8 + i)*ldw + nt*16 + (lane&15)]
// so a wave's B-frag load is one coalesced 16B/lane read. w1: 16384 el, w2: 65536 el.
// ---------------------------------------------------------------------------
__global__ __launch_bounds__(64)
void k0_pack_w1(const float* __restrict__ w1, short* __restrict__ w1f) {
    int o = blockIdx.x * 64 + threadIdx.x;             // < 16384
    int i = o & 7, l = (o >> 3) & 63, ks = (o >> 9) & 3, nt = o >> 11;
    w1f[o] = f2b(w1[(ks * 32 + (l >> 4) * 8 + i) * NCH + nt * 16 + (l & 15)]);
}
__global__ __launch_bounds__(64)
void k0_pack_w2(const float* __restrict__ w2, short* __restrict__ w2f) {
    int o = blockIdx.x * 64 + threadIdx.x;             // < 65536
    int i = o & 7, l = (o >> 3) & 63, ks = (o >> 9) & 3, nt = o >> 11;
    w2f[o] = f2b(w2[(ks * 32 + (l >> 4) * 8 + i) * NK2 + nt * 16 + (l & 15)]);
}

// ---------------------------------------------------------------------------
// k1: MFMA GEMM  acc = sf @ w1  (one wave per 32 rows; bias folds into BN later).
// Also emits bf16 copy of s_feats (sf_b) for the gather, bf16 t (= acc), and
// deterministic per-block BN partial sums (no atomics).
// A-frag: lane holds A[l&15][(l>>4)*8 + i]; D: col=l&15, row=(l>>4)*4+r (m89/m91).
// ---------------------------------------------------------------------------
__global__ __launch_bounds__(64)
void k1_gemm(const float* __restrict__ sf, const short* __restrict__ w1f,
             short* __restrict__ t, short* __restrict__ sfb,
             float* __restrict__ pS, float* __restrict__ pSS) {
    const int l = threadIdx.x, lr = l & 15, lg = l >> 4;
    const int m0 = blockIdx.x * 32;

    // load A fragments (f32 -> bf16), write sf_b copy
    short8 af[2][4];
    #pragma unroll
    for (int mt = 0; mt < 2; ++mt) {
        const int row = m0 + mt * 16 + lr;
        const bool valid = row < MPTS;
        #pragma unroll
        for (int ks = 0; ks < 4; ++ks) {
            const int col = ks * 32 + lg * 8;
            float4v v0 = {0.f, 0.f, 0.f, 0.f}, v1 = {0.f, 0.f, 0.f, 0.f};
            if (valid) {
                const float4v* p = (const float4v*)(sf + (size_t)row * NCH + col);
                v0 = p[0]; v1 = p[1];
            }
            short8 av;
            av[0] = f2b(v0[0]); av[1] = f2b(v0[1]); av[2] = f2b(v0[2]); av[3] = f2b(v0[3]);
            av[4] = f2b(v1[0]); av[5] = f2b(v1[1]); av[6] = f2b(v1[2]); av[7] = f2b(v1[3]);
            af[mt][ks] = av;
            if (valid) *(short8*)(sfb + (size_t)row * NCH + col) = av;
        }
    }

    float4v acc[2][8];
    #pragma unroll
    for (int mt = 0; mt < 2; ++mt)
        #pragma unroll
        for (int nt = 0; nt < 8; ++nt) acc[mt][nt] = (float4v){0.f, 0.f, 0.f, 0.f};

    #pragma unroll
    for (int nt = 0; nt < 8; ++nt) {
        short8 bq[4];
        #pragma unroll
        for (int ks = 0; ks < 4; ++ks)
            bq[ks] = *(const short8*)(w1f + ((nt * 4 + ks) * 64 + l) * 8);
        #pragma unroll
        for (int ks = 0; ks < 4; ++ks) {
            acc[0][nt] = __builtin_amdgcn_mfma_f32_16x16x32_bf16(af[0][ks], bq[ks], acc[0][nt], 0, 0, 0);
            acc[1][nt] = __builtin_amdgcn_mfma_f32_16x16x32_bf16(af[1][ks], bq[ks], acc[1][nt], 0, 0, 0);
        }
    }

    // epilogue: store t (bf16, pad rows store 0 since their acc==0), BN partials
    #pragma unroll
    for (int nt = 0; nt < 8; ++nt) {
        const int cch = nt * 16 + lr;
        float s = 0.f, ss = 0.f;
        #pragma unroll
        for (int mt = 0; mt < 2; ++mt) {
            #pragma unroll
            for (int r = 0; r < 4; ++r) {
                const float v = acc[mt][nt][r];
                const int row = m0 + mt * 16 + lg * 4 + r;   // < 50016 <= TPAD_ROWS
                t[(size_t)row * NCH + cch] = f2b(v);
                s += v; ss += v * v;                          // pad rows add 0 - harmless
            }
        }
        s  += __shfl_xor(s, 16);  s  += __shfl_xor(s, 32);
        ss += __shfl_xor(ss, 16); ss += __shfl_xor(ss, 32);
        if (lg == 0) {
            pS [blockIdx.x * NCH + cch] = s;
            pSS[blockIdx.x * NCH + cch] = ss;
        }
    }
}

// ---------------------------------------------------------------------------
// k2: reduce partials -> BN coefficients.  h = acc*a + b with
//   a = gamma * rsqrt(var + eps),  b = beta - mu_acc * a    (b1 cancels in BN)
// ---------------------------------------------------------------------------
__global__ __launch_bounds__(128)
void k2_coef(const float* __restrict__ pS, const float* __restrict__ pSS,
             const float* __restrict__ gamma, const float* __restrict__ beta,
             float* __restrict__ coef) {
    const int c = threadIdx.x;
    float s = 0.f, ss = 0.f;
    #pragma unroll 4
    for (int b = 0; b < K1_BLOCKS; ++b) {
        s  += pS [b * NCH + c];
        ss += pSS[b * NCH + c];
    }
    const float inv = 1.0f / (float)MPTS;
    const float mu  = s * inv;
    const float var = ss * inv - mu * mu;
    const float a   = gamma[c] * rsqrtf(var + BN_EPS);
    coef[c]       = a;
    coef[NCH + c] = beta[c] - mu * a;
}

// ---------------------------------------------------------------------------
// k3: per 32-point tile:
//   A) h = leaky(t*a+b) -> bf16 LDS, chunk-XOR-swizzled (conflict-free ds_read_b128)
//   B) attn = h @ w2 + b2 via MFMA (B-frags coalesced from w2f), store bf16 to
//      transposed LDS attnT[512][36] (packed 8B writes, padded rows)
//   C) gather: out[m][c] = sum_h sf_b[idx[m][h]][c] * attnT[h*16 + c/8][m]
// ---------------------------------------------------------------------------
__global__ __launch_bounds__(256)
void k3_fused(const short* __restrict__ t, const float* __restrict__ coef,
              const short* __restrict__ w2f, const float* __restrict__ b2,
              const short* __restrict__ sfb, const int* __restrict__ nidx,
              float* __restrict__ out) {
    __shared__ short hsh[512 * 8];       //  8 KB: 32 rows x 16 chunks(16B), swizzled
    __shared__ short attnT[NK2 * 36];    // 36 KB: attnT[n][m], rows padded to 72B
    __shared__ int   idxs[32 * NH];      //  4 KB

    const int tid = threadIdx.x;
    const int m0  = blockIdx.x * 32;

    // ---- stage A ----
    #pragma unroll
    for (int g = tid; g < 512; g += 256) {
        const int row = g >> 4, ch = g & 15;
        short8 tv = *(const short8*)(t + (size_t)(m0 + row) * NCH + ch * 8);
        const float4v* ca = (const float4v*)(coef + ch * 8);
        const float4v* cb = (const float4v*)(coef + NCH + ch * 8);
        const float4v a0 = ca[0], a1 = ca[1], b0 = cb[0], b1 = cb[1];
        short8 hv;
        #pragma unroll
        for (int j = 0; j < 4; ++j) {
            float x = b2f(tv[j]) * a0[j] + b0[j];
            x = (x >= 0.f) ? x : NEG * x;
            hv[j] = f2b(x);
        }
        #pragma unroll
        for (int j = 0; j < 4; ++j) {
            float x = b2f(tv[4 + j]) * a1[j] + b1[j];
            x = (x >= 0.f) ? x : NEG * x;
            hv[4 + j] = f2b(x);
        }
        *(short8*)&hsh[(row * 16 + (ch ^ (row & 15))) * 8] = hv;
    }
    for (int i2 = tid; i2 < 32 * NH; i2 += 256) {
        const int gi = m0 * NH + i2;
        idxs[i2] = (gi < MPTS * NH) ? nidx[gi] : 0;
    }
    __syncthreads();

    // ---- stage B: attn tile MFMA ----
    {
        const int l = tid & 63, w = tid >> 6, lr = l & 15, lg = l >> 4;
        short8 af[2][4];
        #pragma unroll
        for (int mt = 0; mt < 2; ++mt)
            #pragma unroll
            for (int ks = 0; ks < 4; ++ks)
                af[mt][ks] = *(const short8*)&hsh[((mt * 16 + lr) * 16 + ((ks * 4 + lg) ^ lr)) * 8];

        #pragma unroll
        for (int nti = 0; nti < 8; ++nti) {
            const int nt = w * 8 + nti;
            float4v acc0 = {0.f, 0.f, 0.f, 0.f}, acc1 = {0.f, 0.f, 0.f, 0.f};
            #pragma unroll
            for (int ks = 0; ks < 4; ++ks) {
                const short8 bq = *(const short8*)(w2f + ((nt * 4 + ks) * 64 + l) * 8);
                acc0 = __builtin_amdgcn_mfma_f32_16x16x32_bf16(af[0][ks], bq, acc0, 0, 0, 0);
                acc1 = __builtin_amdgcn_mfma_f32_16x16x32_bf16(af[1][ks], bq, acc1, 0, 0, 0);
            }
            const int   n    = nt * 16 + lr;
            const float bias = b2[n];
            // lane holds rows (lg*4 + r) of m-tile mt, col n; pack 4 bf16 -> 8B write
            {
                unsigned u0 = ((unsigned)(unsigned short)f2b(acc0[1] + bias) << 16) |
                               (unsigned short)f2b(acc0[0] + bias);
                unsigned u1 = ((unsigned)(unsigned short)f2b(acc0[3] + bias) << 16) |
                               (unsigned short)f2b(acc0[2] + bias);
                *(uint2v*)&attnT[n * 36 + 0 * 16 + lg * 4] = (uint2v){u0, u1};
            }
            {
                unsigned u0 = ((unsigned)(unsigned short)f2b(acc1[1] + bias) << 16) |
                               (unsigned short)f2b(acc1[0] + bias);
                unsigned u1 = ((unsigned)(unsigned short)f2b(acc1[3] + bias) << 16) |
                               (unsigned short)f2b(acc1[2] + bias);
                *(uint2v*)&attnT[n * 36 + 1 * 16 + lg * 4] = (uint2v){u0, u1};
            }
        }
    }
    __syncthreads();

    // ---- stage C: gather + weighted reduce over H ----
    {
        const int q = tid & 31, pg = tid >> 5;
        const int c0 = q * 4, cpg = q >> 1;
        #pragma unroll
        for (int pi = 0; pi < 4; ++pi) {
            const int p = pg * 4 + pi, m = m0 + p;
            if (m >= MPTS) continue;
            float4v acc = {0.f, 0.f, 0.f, 0.f};
            #pragma unroll 16
            for (int h = 0; h < NH; ++h) {
                const int n = idxs[p * NH + h];
                const uint2v ld = *(const uint2v*)(sfb + (size_t)n * NCH + c0);
                const float wgt = b2f(attnT[(h * 16 + cpg) * 36 + p]);
                const short* fs = (const short*)&ld;
                acc[0] += b2f(fs[0]) * wgt;
                acc[1] += b2f(fs[1]) * wgt;
                acc[2] += b2f(fs[2]) * wgt;
                acc[3] += b2f(fs[3]) * wgt;
            }
            *(float4v*)(out + (size_t)m * NCH + c0) = acc;
        }
    }
}

// ---------------------------------------------------------------------------
extern "C" void kernel_launch(void* const* d_in, const int* in_sizes, int n_in,
                              void* d_out, int out_size, void* d_ws, size_t ws_size,
                              hipStream_t stream) {
    // 0 q_pts | 1 s_pts | 2 s_feats | 3 neighb_inds | 4 w1 | 5 b1 | 6 gamma1
    // 7 beta1 | 8 w2 | 9 b2     (b1 cancels through training-mode BN)
    const float* sf    = (const float*)d_in[2];
    const int*   nidx  = (const int*)  d_in[3];
    const float* w1    = (const float*)d_in[4];
    const float* gamma = (const float*)d_in[6];
    const float* beta  = (const float*)d_in[7];
    const float* w2    = (const float*)d_in[8];
    const float* b2    = (const float*)d_in[9];
    float* out = (float*)d_out;

    short* t   = (short*)d_ws;                       // TPAD_ROWS*128 bf16 = 12.81 MB
    short* sfb = t + (size_t)TPAD_ROWS * NCH;        // TPAD_ROWS*128 bf16 = 12.81 MB
    short* w1f = sfb + (size_t)TPAD_ROWS * NCH;      // 16384 bf16
    short* w2f = w1f + 16384;                        // 65536 bf16
    float* pS  = (float*)(w2f + 65536);              // 1563*128 f32
    float* pSS = pS + (size_t)K1_BLOCKS * NCH;       // 1563*128 f32
    float* coef = pSS + (size_t)K1_BLOCKS * NCH;     // 256 f32
    // total ~27.4 MB of ws

    k0_pack_w1<<<256,  64, 0, stream>>>(w1, w1f);
    k0_pack_w2<<<1024, 64, 0, stream>>>(w2, w2f);
    k1_gemm<<<K1_BLOCKS, 64, 0, stream>>>(sf, w1f, t, sfb, pS, pSS);
    k2_coef<<<1, 128, 0, stream>>>(pS, pSS, gamma, beta, coef);
    k3_fused<<<K1_BLOCKS, 256, 0, stream>>>(t, coef, w2f, b2, sfb, nidx, out);
}

// Round 3
// 89.921 us; speedup vs baseline: 3.2698x; 3.2698x over previous
//
#include <hip/hip_runtime.h>
#include <hip/hip_bf16.h>

#define MPTS  50000
#define NCH   128     // C
#define NH    32      // neighborhood
#define NK2   512     // H * CPG
#define NEG   0.1f
#define BN_EPS 1e-5f
#define K1_BLOCKS 1563        // ceil(50000/32); 1563*32 = 50016
#define TPAD_ROWS 50048
#define R1_CHUNK  17          // k2a rows per block
#define R1_BLOCKS 92          // ceil(1563/17)

typedef __attribute__((ext_vector_type(8))) short        short8;   // 8 bf16 (4 VGPRs) - MFMA A/B frag
typedef __attribute__((ext_vector_type(4))) float        float4v;  // MFMA C/D frag
typedef __attribute__((ext_vector_type(2))) unsigned int uint2v;

__device__ __forceinline__ short f2b(float f) {
    __hip_bfloat16 h = __float2bfloat16(f);
    return *reinterpret_cast<short*>(&h);
}
__device__ __forceinline__ float b2f(short s) {
    unsigned int u = ((unsigned int)(unsigned short)s) << 16;
    return *reinterpret_cast<float*>(&u);
}

// ---------------------------------------------------------------------------
// k0: pre-pack weights into B-fragment-linear bf16 order:
//   wf[((nt*4 + ks)*64 + lane)*8 + i] = w[(ks*32 + (lane>>4)*8 + i)*ldw + nt*16 + (lane&15)]
// so a wave's B-frag load is one coalesced 16B/lane read. w1: 16384 el, w2: 65536 el.
// ---------------------------------------------------------------------------
__global__ __launch_bounds__(64)
void k0_pack_w1(const float* __restrict__ w1, short* __restrict__ w1f) {
    int o = blockIdx.x * 64 + threadIdx.x;             // < 16384
    int i = o & 7, l = (o >> 3) & 63, ks = (o >> 9) & 3, nt = o >> 11;
    w1f[o] = f2b(w1[(ks * 32 + (l >> 4) * 8 + i) * NCH + nt * 16 + (l & 15)]);
}
__global__ __launch_bounds__(64)
void k0_pack_w2(const float* __restrict__ w2, short* __restrict__ w2f) {
    int o = blockIdx.x * 64 + threadIdx.x;             // < 65536
    int i = o & 7, l = (o >> 3) & 63, ks = (o >> 9) & 3, nt = o >> 11;
    w2f[o] = f2b(w2[(ks * 32 + (l >> 4) * 8 + i) * NK2 + nt * 16 + (l & 15)]);
}

// ---------------------------------------------------------------------------
// k1: MFMA GEMM  acc = sf @ w1  (one wave per 32 rows; bias folds into BN later).
// Also emits bf16 copy of s_feats (sf_b) for the gather, bf16 t (= acc), and
// deterministic per-block BN partial sums (no atomics).
// A-frag: lane holds A[l&15][(l>>4)*8 + i]; D: col=l&15, row=(l>>4)*4+r (m89/m91).
// ---------------------------------------------------------------------------
__global__ __launch_bounds__(64)
void k1_gemm(const float* __restrict__ sf, const short* __restrict__ w1f,
             short* __restrict__ t, short* __restrict__ sfb,
             float* __restrict__ pS, float* __restrict__ pSS) {
    const int l = threadIdx.x, lr = l & 15, lg = l >> 4;
    const int m0 = blockIdx.x * 32;

    // load A fragments (f32 -> bf16), write sf_b copy
    short8 af[2][4];
    #pragma unroll
    for (int mt = 0; mt < 2; ++mt) {
        const int row = m0 + mt * 16 + lr;
        const bool valid = row < MPTS;
        #pragma unroll
        for (int ks = 0; ks < 4; ++ks) {
            const int col = ks * 32 + lg * 8;
            float4v v0 = {0.f, 0.f, 0.f, 0.f}, v1 = {0.f, 0.f, 0.f, 0.f};
            if (valid) {
                const float4v* p = (const float4v*)(sf + (size_t)row * NCH + col);
                v0 = p[0]; v1 = p[1];
            }
            short8 av;
            av[0] = f2b(v0[0]); av[1] = f2b(v0[1]); av[2] = f2b(v0[2]); av[3] = f2b(v0[3]);
            av[4] = f2b(v1[0]); av[5] = f2b(v1[1]); av[6] = f2b(v1[2]); av[7] = f2b(v1[3]);
            af[mt][ks] = av;
            if (valid) *(short8*)(sfb + (size_t)row * NCH + col) = av;
        }
    }

    float4v acc[2][8];
    #pragma unroll
    for (int mt = 0; mt < 2; ++mt)
        #pragma unroll
        for (int nt = 0; nt < 8; ++nt) acc[mt][nt] = (float4v){0.f, 0.f, 0.f, 0.f};

    #pragma unroll
    for (int nt = 0; nt < 8; ++nt) {
        short8 bq[4];
        #pragma unroll
        for (int ks = 0; ks < 4; ++ks)
            bq[ks] = *(const short8*)(w1f + ((nt * 4 + ks) * 64 + l) * 8);
        #pragma unroll
        for (int ks = 0; ks < 4; ++ks) {
            acc[0][nt] = __builtin_amdgcn_mfma_f32_16x16x32_bf16(af[0][ks], bq[ks], acc[0][nt], 0, 0, 0);
            acc[1][nt] = __builtin_amdgcn_mfma_f32_16x16x32_bf16(af[1][ks], bq[ks], acc[1][nt], 0, 0, 0);
        }
    }

    // epilogue: store t (bf16, pad rows store 0 since their acc==0), BN partials
    #pragma unroll
    for (int nt = 0; nt < 8; ++nt) {
        const int cch = nt * 16 + lr;
        float s = 0.f, ss = 0.f;
        #pragma unroll
        for (int mt = 0; mt < 2; ++mt) {
            #pragma unroll
            for (int r = 0; r < 4; ++r) {
                const float v = acc[mt][nt][r];
                const int row = m0 + mt * 16 + lg * 4 + r;   // < 50016 <= TPAD_ROWS
                t[(size_t)row * NCH + cch] = f2b(v);
                s += v; ss += v * v;                          // pad rows add 0 - harmless
            }
        }
        s  += __shfl_xor(s, 16);  s  += __shfl_xor(s, 32);
        ss += __shfl_xor(ss, 16); ss += __shfl_xor(ss, 32);
        if (lg == 0) {
            pS [blockIdx.x * NCH + cch] = s;
            pSS[blockIdx.x * NCH + cch] = ss;
        }
    }
}

// ---------------------------------------------------------------------------
// k2a: parallel stage-1 reduction of per-block BN partials.
// 92 blocks x 256 threads; thread = (channel c, array a). Block j sums rows
// [j*17, j*17+17) -> q{S,SS}[j*128 + c]. Deterministic (fixed order).
// ---------------------------------------------------------------------------
__global__ __launch_bounds__(256)
void k2a_reduce(const float* __restrict__ pS, const float* __restrict__ pSS,
                float* __restrict__ qS, float* __restrict__ qSS) {
    const int c = threadIdx.x & 127, a = threadIdx.x >> 7;
    const float* __restrict__ src = a ? pSS : pS;
    const int b0 = blockIdx.x * R1_CHUNK;
    float s = 0.f;
    #pragma unroll
    for (int i = 0; i < R1_CHUNK; ++i) {
        const int b = b0 + i;
        if (b < K1_BLOCKS) s += src[b * NCH + c];
    }
    (a ? qSS : qS)[blockIdx.x * NCH + c] = s;
}

// ---------------------------------------------------------------------------
// k2b: stage-2 reduce (92 rows) + BN coefficients.  h = acc*a + b with
//   a = gamma * rsqrt(var + eps),  b = beta - mu_acc * a    (b1 cancels in BN)
// ---------------------------------------------------------------------------
__global__ __launch_bounds__(256)
void k2b_coef(const float* __restrict__ qS, const float* __restrict__ qSS,
              const float* __restrict__ gamma, const float* __restrict__ beta,
              float* __restrict__ coef) {
    __shared__ float sh[256];
    const int c = threadIdx.x & 127, a = threadIdx.x >> 7;
    const float* __restrict__ src = a ? qSS : qS;
    float s0 = 0.f, s1 = 0.f, s2 = 0.f, s3 = 0.f;
    #pragma unroll
    for (int b = 0; b < R1_BLOCKS; b += 4) {             // 92 = 4*23
        s0 += src[(b + 0) * NCH + c];
        s1 += src[(b + 1) * NCH + c];
        s2 += src[(b + 2) * NCH + c];
        s3 += src[(b + 3) * NCH + c];
    }
    sh[threadIdx.x] = (s0 + s1) + (s2 + s3);
    __syncthreads();
    if (a == 0) {
        const float inv = 1.0f / (float)MPTS;
        const float mu  = sh[c] * inv;
        const float var = sh[128 + c] * inv - mu * mu;
        const float aa  = gamma[c] * rsqrtf(var + BN_EPS);
        coef[c]       = aa;
        coef[NCH + c] = beta[c] - mu * aa;
    }
}

// ---------------------------------------------------------------------------
// k3: per 32-point tile:
//   A) h = leaky(t*a+b) -> bf16 LDS, chunk-XOR-swizzled (conflict-free ds_read_b128)
//   B) attn = h @ w2 + b2 via MFMA (B-frags coalesced from w2f), store bf16 to
//      transposed LDS attnT[512][36] (packed 8B writes, padded rows)
//   C) gather: out[m][c] = sum_h sf_b[idx[m][h]][c] * attnT[h*16 + c/8][m]
// ---------------------------------------------------------------------------
__global__ __launch_bounds__(256)
void k3_fused(const short* __restrict__ t, const float* __restrict__ coef,
              const short* __restrict__ w2f, const float* __restrict__ b2,
              const short* __restrict__ sfb, const int* __restrict__ nidx,
              float* __restrict__ out) {
    __shared__ short hsh[512 * 8];       //  8 KB: 32 rows x 16 chunks(16B), swizzled
    __shared__ short attnT[NK2 * 36];    // 36 KB: attnT[n][m], rows padded to 72B
    __shared__ int   idxs[32 * NH];      //  4 KB

    const int tid = threadIdx.x;
    const int m0  = blockIdx.x * 32;

    // ---- stage A ----
    #pragma unroll
    for (int g = tid; g < 512; g += 256) {
        const int row = g >> 4, ch = g & 15;
        short8 tv = *(const short8*)(t + (size_t)(m0 + row) * NCH + ch * 8);
        const float4v* ca = (const float4v*)(coef + ch * 8);
        const float4v* cb = (const float4v*)(coef + NCH + ch * 8);
        const float4v a0 = ca[0], a1 = ca[1], b0 = cb[0], b1 = cb[1];
        short8 hv;
        #pragma unroll
        for (int j = 0; j < 4; ++j) {
            float x = b2f(tv[j]) * a0[j] + b0[j];
            x = (x >= 0.f) ? x : NEG * x;
            hv[j] = f2b(x);
        }
        #pragma unroll
        for (int j = 0; j < 4; ++j) {
            float x = b2f(tv[4 + j]) * a1[j] + b1[j];
            x = (x >= 0.f) ? x : NEG * x;
            hv[4 + j] = f2b(x);
        }
        *(short8*)&hsh[(row * 16 + (ch ^ (row & 15))) * 8] = hv;
    }
    for (int i2 = tid; i2 < 32 * NH; i2 += 256) {
        const int gi = m0 * NH + i2;
        idxs[i2] = (gi < MPTS * NH) ? nidx[gi] : 0;
    }
    __syncthreads();

    // ---- stage B: attn tile MFMA ----
    {
        const int l = tid & 63, w = tid >> 6, lr = l & 15, lg = l >> 4;
        short8 af[2][4];
        #pragma unroll
        for (int mt = 0; mt < 2; ++mt)
            #pragma unroll
            for (int ks = 0; ks < 4; ++ks)
                af[mt][ks] = *(const short8*)&hsh[((mt * 16 + lr) * 16 + ((ks * 4 + lg) ^ lr)) * 8];

        #pragma unroll
        for (int nti = 0; nti < 8; ++nti) {
            const int nt = w * 8 + nti;
            float4v acc0 = {0.f, 0.f, 0.f, 0.f}, acc1 = {0.f, 0.f, 0.f, 0.f};
            #pragma unroll
            for (int ks = 0; ks < 4; ++ks) {
                const short8 bq = *(const short8*)(w2f + ((nt * 4 + ks) * 64 + l) * 8);
                acc0 = __builtin_amdgcn_mfma_f32_16x16x32_bf16(af[0][ks], bq, acc0, 0, 0, 0);
                acc1 = __builtin_amdgcn_mfma_f32_16x16x32_bf16(af[1][ks], bq, acc1, 0, 0, 0);
            }
            const int   n    = nt * 16 + lr;
            const float bias = b2[n];
            // lane holds rows (lg*4 + r) of m-tile mt, col n; pack 4 bf16 -> 8B write
            {
                unsigned u0 = ((unsigned)(unsigned short)f2b(acc0[1] + bias) << 16) |
                               (unsigned short)f2b(acc0[0] + bias);
                unsigned u1 = ((unsigned)(unsigned short)f2b(acc0[3] + bias) << 16) |
                               (unsigned short)f2b(acc0[2] + bias);
                *(uint2v*)&attnT[n * 36 + 0 * 16 + lg * 4] = (uint2v){u0, u1};
            }
            {
                unsigned u0 = ((unsigned)(unsigned short)f2b(acc1[1] + bias) << 16) |
                               (unsigned short)f2b(acc1[0] + bias);
                unsigned u1 = ((unsigned)(unsigned short)f2b(acc1[3] + bias) << 16) |
                               (unsigned short)f2b(acc1[2] + bias);
                *(uint2v*)&attnT[n * 36 + 1 * 16 + lg * 4] = (uint2v){u0, u1};
            }
        }
    }
    __syncthreads();

    // ---- stage C: gather + weighted reduce over H ----
    {
        const int q = tid & 31, pg = tid >> 5;
        const int c0 = q * 4, cpg = q >> 1;
        #pragma unroll
        for (int pi = 0; pi < 4; ++pi) {
            const int p = pg * 4 + pi, m = m0 + p;
            if (m >= MPTS) continue;
            float4v acc = {0.f, 0.f, 0.f, 0.f};
            #pragma unroll 16
            for (int h = 0; h < NH; ++h) {
                const int n = idxs[p * NH + h];
                const uint2v ld = *(const uint2v*)(sfb + (size_t)n * NCH + c0);
                const float wgt = b2f(attnT[(h * 16 + cpg) * 36 + p]);
                const short* fs = (const short*)&ld;
                acc[0] += b2f(fs[0]) * wgt;
                acc[1] += b2f(fs[1]) * wgt;
                acc[2] += b2f(fs[2]) * wgt;
                acc[3] += b2f(fs[3]) * wgt;
            }
            *(float4v*)(out + (size_t)m * NCH + c0) = acc;
        }
    }
}

// ---------------------------------------------------------------------------
extern "C" void kernel_launch(void* const* d_in, const int* in_sizes, int n_in,
                              void* d_out, int out_size, void* d_ws, size_t ws_size,
                              hipStream_t stream) {
    // 0 q_pts | 1 s_pts | 2 s_feats | 3 neighb_inds | 4 w1 | 5 b1 | 6 gamma1
    // 7 beta1 | 8 w2 | 9 b2     (b1 cancels through training-mode BN)
    const float* sf    = (const float*)d_in[2];
    const int*   nidx  = (const int*)  d_in[3];
    const float* w1    = (const float*)d_in[4];
    const float* gamma = (const float*)d_in[6];
    const float* beta  = (const float*)d_in[7];
    const float* w2    = (const float*)d_in[8];
    const float* b2    = (const float*)d_in[9];
    float* out = (float*)d_out;

    short* t   = (short*)d_ws;                       // TPAD_ROWS*128 bf16 = 12.81 MB
    short* sfb = t + (size_t)TPAD_ROWS * NCH;        // TPAD_ROWS*128 bf16 = 12.81 MB
    short* w1f = sfb + (size_t)TPAD_ROWS * NCH;      // 16384 bf16
    short* w2f = w1f + 16384;                        // 65536 bf16
    float* pS  = (float*)(w2f + 65536);              // 1563*128 f32
    float* pSS = pS + (size_t)K1_BLOCKS * NCH;       // 1563*128 f32
    float* qS  = pSS + (size_t)K1_BLOCKS * NCH;      // 92*128 f32
    float* qSS = qS + (size_t)R1_BLOCKS * NCH;       // 92*128 f32
    float* coef = qSS + (size_t)R1_BLOCKS * NCH;     // 256 f32
    // total ~27.5 MB of ws

    k0_pack_w1<<<256,  64, 0, stream>>>(w1, w1f);
    k0_pack_w2<<<1024, 64, 0, stream>>>(w2, w2f);
    k1_gemm<<<K1_BLOCKS, 64, 0, stream>>>(sf, w1f, t, sfb, pS, pSS);
    k2a_reduce<<<R1_BLOCKS, 256, 0, stream>>>(pS, pSS, qS, qSS);
    k2b_coef<<<1, 256, 0, stream>>>(qS, qSS, gamma, beta, coef);
    k3_fused<<<K1_BLOCKS, 256, 0, stream>>>(t, coef, w2f, b2, sfb, nidx, out);
}

// Round 4
// 79.407 us; speedup vs baseline: 3.7027x; 1.1324x over previous
//
#include <hip/hip_runtime.h>
#include <hip/hip_bf16.h>

#define MPTS  50000
#define NCH   128     // C
#define NH    32      // neighborhood
#define NK2   512     // H * CPG
#define NEG   0.1f
#define BN_EPS 1e-5f
#define K1T   1564            // padded tile count (each tile = 32 rows); 391 blocks x 4 waves
#define TPAD_ROWS 50048       // 1564*32
#define R1_CHUNK  17          // k2a rows per block
#define R1_BLOCKS 92          // 92*17 = 1564 exactly
#define K3_BLOCKS 3125        // 50000/16
#define ATP 20                // attnT row pad (shorts): 40B rows, 8B-aligned, bank-clean

typedef __attribute__((ext_vector_type(8))) short        short8;   // 8 bf16 - MFMA A/B frag
typedef __attribute__((ext_vector_type(4))) float        float4v;  // MFMA C/D frag
typedef __attribute__((ext_vector_type(2))) unsigned int uint2v;
typedef __attribute__((ext_vector_type(4))) unsigned int uint4v;

__device__ __forceinline__ short f2b(float f) {
    __hip_bfloat16 h = __float2bfloat16(f);
    return *reinterpret_cast<short*>(&h);
}
__device__ __forceinline__ float b2f(short s) {
    unsigned int u = ((unsigned int)(unsigned short)s) << 16;
    return *reinterpret_cast<float*>(&u);
}
__device__ __forceinline__ float b2f_hi(unsigned int w) {
    unsigned int u = w & 0xffff0000u;
    return *reinterpret_cast<float*>(&u);
}
__device__ __forceinline__ float b2f_lo(unsigned int w) {
    unsigned int u = w << 16;
    return *reinterpret_cast<float*>(&u);
}

// ---------------------------------------------------------------------------
// k0: pack w1 (16384 el) and w2 (65536 el) into B-fragment-linear bf16:
//   wf[((nt*4+ks)*64 + l)*8 + i] = w[(ks*32 + (l>>4)*8 + i)*ldw + nt*16 + (l&15)]
// One merged launch: blocks [0,256) -> w1, [256,1280) -> w2.
// ---------------------------------------------------------------------------
__global__ __launch_bounds__(64)
void k0_pack(const float* __restrict__ w1, const float* __restrict__ w2,
             short* __restrict__ w1f, short* __restrict__ w2f) {
    if (blockIdx.x < 256) {
        int o = blockIdx.x * 64 + threadIdx.x;             // < 16384
        int i = o & 7, l = (o >> 3) & 63, ks = (o >> 9) & 3, nt = o >> 11;
        w1f[o] = f2b(w1[(ks * 32 + (l >> 4) * 8 + i) * NCH + nt * 16 + (l & 15)]);
    } else {
        int o = (blockIdx.x - 256) * 64 + threadIdx.x;     // < 65536
        int i = o & 7, l = (o >> 3) & 63, ks = (o >> 9) & 3, nt = o >> 11;
        w2f[o] = f2b(w2[(ks * 32 + (l >> 4) * 8 + i) * NK2 + nt * 16 + (l & 15)]);
    }
}

// ---------------------------------------------------------------------------
// k1: MFMA GEMM  acc = sf @ w1  (4 waves/block, wave = one 32-row tile).
// Outputs:
//   tfrag : bf16 acc in fragment-linear layout, uint2 packed:
//           tfrag[((tile*2+mt)*8+nt)*64 + l] = rows (l>>4)*4..+3, col nt*16+(l&15)
//   sfb   : bf16 copy of s_feats (row-major) for the gather
//   pS/pSS: deterministic per-tile BN partial sums (padded tiles contribute 0)
// ---------------------------------------------------------------------------
__global__ __launch_bounds__(256)
void k1_gemm(const float* __restrict__ sf, const short* __restrict__ w1f,
             uint2v* __restrict__ tfrag, short* __restrict__ sfb,
             float* __restrict__ pS, float* __restrict__ pSS) {
    const int l = threadIdx.x & 63, lr = l & 15, lg = l >> 4;
    const int tile = blockIdx.x * 4 + (threadIdx.x >> 6);   // < 1564
    const int m0 = tile * 32;

    // load A fragments (f32 -> bf16), write sfb copy
    short8 af[2][4];
    #pragma unroll
    for (int mt = 0; mt < 2; ++mt) {
        const int row = m0 + mt * 16 + lr;
        const bool valid = row < MPTS;
        #pragma unroll
        for (int ks = 0; ks < 4; ++ks) {
            const int col = ks * 32 + lg * 8;
            float4v v0 = {0.f, 0.f, 0.f, 0.f}, v1 = {0.f, 0.f, 0.f, 0.f};
            if (valid) {
                const float4v* p = (const float4v*)(sf + (size_t)row * NCH + col);
                v0 = p[0]; v1 = p[1];
            }
            short8 av;
            av[0] = f2b(v0[0]); av[1] = f2b(v0[1]); av[2] = f2b(v0[2]); av[3] = f2b(v0[3]);
            av[4] = f2b(v1[0]); av[5] = f2b(v1[1]); av[6] = f2b(v1[2]); av[7] = f2b(v1[3]);
            af[mt][ks] = av;
            if (valid) *(short8*)(sfb + (size_t)row * NCH + col) = av;
        }
    }

    float4v acc[2][8];
    #pragma unroll
    for (int mt = 0; mt < 2; ++mt)
        #pragma unroll
        for (int nt = 0; nt < 8; ++nt) acc[mt][nt] = (float4v){0.f, 0.f, 0.f, 0.f};

    #pragma unroll
    for (int nt = 0; nt < 8; ++nt) {
        short8 bq[4];
        #pragma unroll
        for (int ks = 0; ks < 4; ++ks)
            bq[ks] = *(const short8*)(w1f + ((nt * 4 + ks) * 64 + l) * 8);
        #pragma unroll
        for (int ks = 0; ks < 4; ++ks) {
            acc[0][nt] = __builtin_amdgcn_mfma_f32_16x16x32_bf16(af[0][ks], bq[ks], acc[0][nt], 0, 0, 0);
            acc[1][nt] = __builtin_amdgcn_mfma_f32_16x16x32_bf16(af[1][ks], bq[ks], acc[1][nt], 0, 0, 0);
        }
    }

    // epilogue: packed fragment-linear t stores + BN partials
    #pragma unroll
    for (int nt = 0; nt < 8; ++nt) {
        const int cch = nt * 16 + lr;
        float s = 0.f, ss = 0.f;
        #pragma unroll
        for (int mt = 0; mt < 2; ++mt) {
            const float4v a = acc[mt][nt];
            unsigned u0 = ((unsigned)(unsigned short)f2b(a[1]) << 16) | (unsigned short)f2b(a[0]);
            unsigned u1 = ((unsigned)(unsigned short)f2b(a[3]) << 16) | (unsigned short)f2b(a[2]);
            tfrag[(size_t)((tile * 2 + mt) * 8 + nt) * 64 + l] = (uint2v){u0, u1};
            s  += a[0] + a[1] + a[2] + a[3];
            ss += a[0]*a[0] + a[1]*a[1] + a[2]*a[2] + a[3]*a[3];
        }
        s  += __shfl_xor(s, 16);  s  += __shfl_xor(s, 32);
        ss += __shfl_xor(ss, 16); ss += __shfl_xor(ss, 32);
        if (lg == 0) {
            pS [tile * NCH + cch] = s;
            pSS[tile * NCH + cch] = ss;
        }
    }
}

// ---------------------------------------------------------------------------
// k2a: stage-1 reduction of per-tile BN partials. 92 blocks x 17 rows = 1564.
// ---------------------------------------------------------------------------
__global__ __launch_bounds__(256)
void k2a_reduce(const float* __restrict__ pS, const float* __restrict__ pSS,
                float* __restrict__ qS, float* __restrict__ qSS) {
    const int c = threadIdx.x & 127, a = threadIdx.x >> 7;
    const float* __restrict__ src = a ? pSS : pS;
    const int b0 = blockIdx.x * R1_CHUNK;
    float s = 0.f;
    #pragma unroll
    for (int i = 0; i < R1_CHUNK; ++i)
        s += src[(b0 + i) * NCH + c];
    (a ? qSS : qS)[blockIdx.x * NCH + c] = s;
}

// ---------------------------------------------------------------------------
// k2b: stage-2 reduce (92 rows) + BN coefficients. h = acc*a + b with
//   a = gamma * rsqrt(var + eps),  b = beta - mu*a    (b1 cancels in BN)
// ---------------------------------------------------------------------------
__global__ __launch_bounds__(256)
void k2b_coef(const float* __restrict__ qS, const float* __restrict__ qSS,
              const float* __restrict__ gamma, const float* __restrict__ beta,
              float* __restrict__ coef) {
    __shared__ float sh[256];
    const int c = threadIdx.x & 127, a = threadIdx.x >> 7;
    const float* __restrict__ src = a ? qSS : qS;
    float s0 = 0.f, s1 = 0.f, s2 = 0.f, s3 = 0.f;
    #pragma unroll
    for (int b = 0; b < R1_BLOCKS; b += 4) {             // 92 = 4*23
        s0 += src[(b + 0) * NCH + c];
        s1 += src[(b + 1) * NCH + c];
        s2 += src[(b + 2) * NCH + c];
        s3 += src[(b + 3) * NCH + c];
    }
    sh[threadIdx.x] = (s0 + s1) + (s2 + s3);
    __syncthreads();
    if (a == 0) {
        const float inv = 1.0f / (float)MPTS;
        const float mu  = sh[c] * inv;
        const float var = sh[128 + c] * inv - mu * mu;
        const float aa  = gamma[c] * rsqrtf(var + BN_EPS);
        coef[c]       = aa;
        coef[NCH + c] = beta[c] - mu * aa;
    }
}

// ---------------------------------------------------------------------------
// k3: per 16-point tile (3125 blocks, 256 thr, 26KB LDS -> 6 blocks/CU):
//   A) read tfrag (coalesced uint2), BN+leaky (coef is lane-uniform scalar),
//      write bf16 swizzled hsh[16][128]
//   B) attn = h @ w2 + b2 via MFMA; bf16 transposed LDS attnT[512][ATP]
//   C) gather: thread = (point p, 8-ch slice); 16B uint4 loads of sfb rows
// ---------------------------------------------------------------------------
__global__ __launch_bounds__(256)
void k3_fused(const uint2v* __restrict__ tfrag, const float* __restrict__ coef,
              const short* __restrict__ w2f, const float* __restrict__ b2,
              const short* __restrict__ sfb, const int* __restrict__ nidx,
              float* __restrict__ out) {
    __shared__ short hsh[16 * 128];      //  4 KB, chunk-XOR swizzled
    __shared__ short attnT[NK2 * ATP];   // 20 KB: attnT[n][p], 40B rows
    __shared__ int   idxs[16 * NH];      //  2 KB

    const int tid = threadIdx.x;
    const int m0  = blockIdx.x * 16;

    // ---- stage A: tfrag -> BN -> leaky -> hsh ----
    {
        const int l = tid & 63, half = tid >> 6;
        #pragma unroll
        for (int k = 0; k < 2; ++k) {
            const int nt = half + k * 4;
            const uint2v v = tfrag[(size_t)blockIdx.x * 512 + nt * 64 + l];
            const int col = nt * 16 + (l & 15);
            const int rg  = (l >> 4) * 4;
            const float a = coef[col];
            const float b = coef[NCH + col];
            const int ch  = col >> 3;           // chunk index 0..15
            const int cb  = col & 7;
            float x0 = b2f_lo(v[0]) * a + b;  x0 = (x0 >= 0.f) ? x0 : NEG * x0;
            float x1 = b2f_hi(v[0]) * a + b;  x1 = (x1 >= 0.f) ? x1 : NEG * x1;
            float x2 = b2f_lo(v[1]) * a + b;  x2 = (x2 >= 0.f) ? x2 : NEG * x2;
            float x3 = b2f_hi(v[1]) * a + b;  x3 = (x3 >= 0.f) ? x3 : NEG * x3;
            hsh[((rg + 0) * 16 + (ch ^ (rg + 0))) * 8 + cb] = f2b(x0);
            hsh[((rg + 1) * 16 + (ch ^ (rg + 1))) * 8 + cb] = f2b(x1);
            hsh[((rg + 2) * 16 + (ch ^ (rg + 2))) * 8 + cb] = f2b(x2);
            hsh[((rg + 3) * 16 + (ch ^ (rg + 3))) * 8 + cb] = f2b(x3);
        }
        // neighbor indices: 512 ints, 2 per thread
        idxs[tid]       = nidx[(size_t)m0 * NH + tid];
        idxs[tid + 256] = nidx[(size_t)m0 * NH + tid + 256];
    }
    __syncthreads();

    // ---- stage B: attn = h @ w2 + b2 (MFMA), transposed bf16 -> attnT ----
    {
        const int l = tid & 63, w = tid >> 6, lr = l & 15, lg = l >> 4;
        short8 af[4];
        #pragma unroll
        for (int ks = 0; ks < 4; ++ks)
            af[ks] = *(const short8*)&hsh[(lr * 16 + ((ks * 4 + lg) ^ lr)) * 8];

        #pragma unroll
        for (int nti = 0; nti < 8; ++nti) {
            const int nt = w * 8 + nti;          // 0..31
            float4v acc = {0.f, 0.f, 0.f, 0.f};
            #pragma unroll
            for (int ks = 0; ks < 4; ++ks) {
                const short8 bq = *(const short8*)(w2f + ((nt * 4 + ks) * 64 + l) * 8);
                acc = __builtin_amdgcn_mfma_f32_16x16x32_bf16(af[ks], bq, acc, 0, 0, 0);
            }
            const int   n    = nt * 16 + lr;
            const float bias = b2[n];
            unsigned u0 = ((unsigned)(unsigned short)f2b(acc[1] + bias) << 16) |
                           (unsigned short)f2b(acc[0] + bias);
            unsigned u1 = ((unsigned)(unsigned short)f2b(acc[3] + bias) << 16) |
                           (unsigned short)f2b(acc[2] + bias);
            *(uint2v*)&attnT[n * ATP + lg * 4] = (uint2v){u0, u1};
        }
    }
    __syncthreads();

    // ---- stage C: gather + weighted reduce over H (1 point x 8ch / thread) ----
    {
        const int q = tid & 15, p = tid >> 4;    // q: 8-channel slice, p: point
        const int c0 = q * 8;                    // cpg = q
        const int m = m0 + p;
        float acc0 = 0.f, acc1 = 0.f, acc2 = 0.f, acc3 = 0.f;
        float acc4 = 0.f, acc5 = 0.f, acc6 = 0.f, acc7 = 0.f;
        #pragma unroll 4
        for (int h = 0; h < NH; ++h) {
            const int n = idxs[p * NH + h];
            const uint4v ld = *(const uint4v*)(sfb + (size_t)n * NCH + c0);
            const float wgt = b2f(attnT[(h * 16 + q) * ATP + p]);
            acc0 += b2f_lo(ld[0]) * wgt;
            acc1 += b2f_hi(ld[0]) * wgt;
            acc2 += b2f_lo(ld[1]) * wgt;
            acc3 += b2f_hi(ld[1]) * wgt;
            acc4 += b2f_lo(ld[2]) * wgt;
            acc5 += b2f_hi(ld[2]) * wgt;
            acc6 += b2f_lo(ld[3]) * wgt;
            acc7 += b2f_hi(ld[3]) * wgt;
        }
        float4v o0 = {acc0, acc1, acc2, acc3};
        float4v o1 = {acc4, acc5, acc6, acc7};
        *(float4v*)(out + (size_t)m * NCH + c0)     = o0;
        *(float4v*)(out + (size_t)m * NCH + c0 + 4) = o1;
    }
}

// ---------------------------------------------------------------------------
extern "C" void kernel_launch(void* const* d_in, const int* in_sizes, int n_in,
                              void* d_out, int out_size, void* d_ws, size_t ws_size,
                              hipStream_t stream) {
    // 0 q_pts | 1 s_pts | 2 s_feats | 3 neighb_inds | 4 w1 | 5 b1 | 6 gamma1
    // 7 beta1 | 8 w2 | 9 b2     (b1 cancels through training-mode BN)
    const float* sf    = (const float*)d_in[2];
    const int*   nidx  = (const int*)  d_in[3];
    const float* w1    = (const float*)d_in[4];
    const float* gamma = (const float*)d_in[6];
    const float* beta  = (const float*)d_in[7];
    const float* w2    = (const float*)d_in[8];
    const float* b2    = (const float*)d_in[9];
    float* out = (float*)d_out;

    short*  t    = (short*)d_ws;                     // TPAD_ROWS*128 bf16 = 12.81 MB
    short*  sfb  = t + (size_t)TPAD_ROWS * NCH;      // TPAD_ROWS*128 bf16 = 12.81 MB
    short*  w1f  = sfb + (size_t)TPAD_ROWS * NCH;    // 16384 bf16
    short*  w2f  = w1f + 16384;                      // 65536 bf16
    float*  pS   = (float*)(w2f + 65536);            // 1564*128 f32
    float*  pSS  = pS + (size_t)K1T * NCH;           // 1564*128 f32
    float*  qS   = pSS + (size_t)K1T * NCH;          // 92*128 f32
    float*  qSS  = qS + (size_t)R1_BLOCKS * NCH;     // 92*128 f32
    float*  coef = qSS + (size_t)R1_BLOCKS * NCH;    // 256 f32
    uint2v* tfrag = (uint2v*)t;

    k0_pack<<<1280, 64, 0, stream>>>(w1, w2, w1f, w2f);
    k1_gemm<<<391, 256, 0, stream>>>(sf, w1f, tfrag, sfb, pS, pSS);
    k2a_reduce<<<R1_BLOCKS, 256, 0, stream>>>(pS, pSS, qS, qSS);
    k2b_coef<<<1, 256, 0, stream>>>(qS, qSS, gamma, beta, coef);
    k3_fused<<<K3_BLOCKS, 256, 0, stream>>>(tfrag, coef, w2f, b2, sfb, nidx, out);
}